// Round 18
// baseline (367.502 us; speedup 1.0000x reference)
//
#include <hip/hip_runtime.h>

// ---------------------------------------------------------------------------
// KacLayer: out = x @ (W^T + M) + b, where M = A2 diag(vec) A1 (Kac walks).
// numpy default_rng(4048)/default_rng(4049): PCG64 + SeedSequence (subtractive
// mix) + 32-bit buffered Lemire ints (low u32 half first) — verified r7.
// r16: level-parallel walk (256 blocks), r14-structure GEMM (BK=64 gload_lds,
// 48KB LDS, 3 blocks/CU — 180us verified; r15 big-tile and r17 2-phase both
// regressed). r18: persistent GEMM grid (768 blocks x 2-3 tiles) to remove
// the 2.67-round dispatch tail.
// ---------------------------------------------------------------------------

#define NSTEPS 3072
#define NCHUNK 26
#define NRAW (256 * NCHUNK)   // 6656 u64 (need 6144 + rejection slack)
#define MAXS 4608             // schedule slots per phase (3072 + pads)
#define MAXLEV 256

typedef __attribute__((ext_vector_type(8))) short short8;
typedef __attribute__((ext_vector_type(4))) float f32x4;

// ---------------- 128-bit PCG64 (numpy-exact) ------------------------------
struct U128 { unsigned long long lo, hi; };

__device__ __forceinline__ U128 mul128(U128 a, U128 b) {
  U128 r;
  r.lo = a.lo * b.lo;
  r.hi = __umul64hi(a.lo, b.lo) + a.lo * b.hi + a.hi * b.lo;
  return r;
}
__device__ __forceinline__ U128 add128(U128 a, U128 b) {
  U128 r; r.lo = a.lo + b.lo;
  r.hi = a.hi + b.hi + ((r.lo < a.lo) ? 1ull : 0ull);
  return r;
}
__device__ __forceinline__ U128 pcg_mult() {
  return U128{4865540595714422341ull, 2549297995355413924ull};
}
__device__ __forceinline__ U128 pcg_step(U128 st, U128 inc) {
  return add128(mul128(st, pcg_mult()), inc);
}
__device__ __forceinline__ unsigned long long pcg_out(U128 st) {
  unsigned long long x = st.hi ^ st.lo;
  unsigned int rot = (unsigned int)(st.hi >> 58);
  return (x >> rot) | (x << ((64u - rot) & 63u));
}

__device__ void pcg_seed(unsigned int seedval, U128* st, U128* inc) {
  unsigned int pool[4];
  unsigned int hc = 0x43b0d7e5u;                 // INIT_A
  auto hashmix = [&hc](unsigned int v) {
    v ^= hc; hc *= 0x931e8875u; v *= hc; v ^= v >> 16; return v;  // MULT_A
  };
  auto mixf = [](unsigned int x, unsigned int y) {
    unsigned int r = x * 0xca01f9ddu - y * 0x4973f715u;  // SUBTRACT (randutils)
    r ^= r >> 16; return r;
  };
  pool[0] = hashmix(seedval);
  pool[1] = hashmix(0u); pool[2] = hashmix(0u); pool[3] = hashmix(0u);
  for (int s = 0; s < 4; ++s)
    for (int d = 0; d < 4; ++d)
      if (s != d) pool[d] = mixf(pool[d], hashmix(pool[s]));
  unsigned int gc = 0x8b51f9ddu;                 // INIT_B
  unsigned int wv[8];
  for (int k = 0; k < 8; ++k) {
    unsigned int dv = pool[k & 3];
    dv ^= gc; gc *= 0x58f38dedu; dv *= gc; dv ^= dv >> 16;        // MULT_B
    wv[k] = dv;
  }
  unsigned long long o0 = (unsigned long long)wv[0] | ((unsigned long long)wv[1] << 32);
  unsigned long long o1 = (unsigned long long)wv[2] | ((unsigned long long)wv[3] << 32);
  unsigned long long o2 = (unsigned long long)wv[4] | ((unsigned long long)wv[5] << 32);
  unsigned long long o3 = (unsigned long long)wv[6] | ((unsigned long long)wv[7] << 32);
  U128 initstate = { o1, o0 };
  U128 initseq   = { o3, o2 };
  U128 icc; icc.lo = (initseq.lo << 1) | 1ull;
  icc.hi = (initseq.hi << 1) | (initseq.lo >> 63);
  *inc = icc;
  U128 s0 = {0ull, 0ull};
  s0 = pcg_step(s0, icc);
  s0 = add128(s0, initstate);
  s0 = pcg_step(s0, icc);
  *st = s0;
}

__device__ U128 pcg_advance(U128 st, U128 inc, unsigned long long delta) {
  U128 am = {1ull, 0ull}, ap = {0ull, 0ull};
  U128 cm = pcg_mult(), cp = inc;
  while (delta) {
    if (delta & 1ull) {
      am = mul128(am, cm);
      ap = add128(mul128(ap, cm), cp);
    }
    cp = mul128(add128(cm, U128{1ull, 0ull}), cp);
    cm = mul128(cm, cm);
    delta >>= 1;
  }
  return add128(mul128(st, am), ap);
}

__device__ __forceinline__ double first_draw(unsigned int seed) {
  U128 st, inc;
  pcg_seed(seed, &st, &inc);
  st = pcg_step(st, inc);
  return (double)(pcg_out(st) >> 11) * (1.0 / 9007199254740992.0);
}

__device__ __forceinline__ unsigned short f32_to_bf16(float f) {
  unsigned int u = __builtin_bit_cast(unsigned int, f);
  unsigned int r = u + 0x7fffu + ((u >> 16) & 1u);
  return (unsigned short)(r >> 16);
}

// ---------------- Kernel 1: schedule gen + level scheduling ----------------
__global__ __launch_bounds__(256) void gen_sched_kernel(uint4* __restrict__ ps0,
                                                        uint4* __restrict__ ps1,
                                                        int* __restrict__ hdr,
                                                        int* __restrict__ glb0,
                                                        int* __restrict__ glb1,
                                                        float* __restrict__ diag) {
  __shared__ unsigned long long raw[NRAW];          // 53 KB
  __shared__ unsigned int s_ij[NSTEPS];             // 12 KB
  __shared__ unsigned short s_list[2 * NSTEPS];     // 12 KB  (k<<1 | side)
  __shared__ short s_predA[NSTEPS];                 // 6 KB
  __shared__ short s_predB[NSTEPS];                 // 6 KB
  __shared__ unsigned short s_lev[NSTEPS];          // 6 KB
  __shared__ int s_cnt[1024];                       // 4 KB (also cursors)
  __shared__ int s_base[1025];                      // 4 KB
  __shared__ int s_lcnt[MAXLEV];                    // 1 KB (also cursors)
  __shared__ int s_lbase[MAXLEV];                   // 1 KB
  __shared__ int s_rej, s_p64, s_changed, s_maxlev, s_ns;
  const int w = blockIdx.x;     // walk: seed 4048 + w
  const int t = threadIdx.x;
  int* glbw = w ? glb1 : glb0;

  if (w == 0 && t == 0) {
    int m1 = first_draw(42u)    != 0.7739560485559633;
    int m2 = first_draw(0u)     != 0.6369616873214543;
    int m3 = first_draw(12345u) != 0.22733602246716966;
    if (m1 + m2 + m3 >= 2)
      diag[0] = 3.0e8f + (float)(m1 + 2 * m2 + 4 * m3) * 3.0e7f;
  }

  U128 st, inc;
  pcg_seed(4048u + (unsigned int)w, &st, &inc);
  U128 mine = pcg_advance(st, inc, (unsigned long long)t * NCHUNK);
  for (int q = 0; q < NCHUNK; ++q) {
    mine = pcg_step(mine, inc);
    raw[t * NCHUNK + q] = pcg_out(mine);
  }
  if (t == 0) { s_rej = 0; s_maxlev = 1; }
  __syncthreads();

  // u32 draw m: LOW half of u64 first, then HIGH (pcg64_next32 buffering)
  auto u32at = [&](int m) -> unsigned int {
    unsigned long long v = raw[m >> 1];
    return (m & 1) ? (unsigned int)(v >> 32) : (unsigned int)v;
  };

  for (int k = t; k < NSTEPS; k += 256) {
    unsigned long long m = (unsigned long long)u32at(NSTEPS + k) * 1023ull;
    if ((unsigned int)m < 4u) atomicAdd(&s_rej, 1);
  }
  __syncthreads();

  if (s_rej == 0) {
    for (int k = t; k < NSTEPS; k += 256) {
      unsigned int iv = u32at(k) >> 22;                 // (u32*1024)>>32
      unsigned long long m = (unsigned long long)u32at(NSTEPS + k) * 1023ull;
      unsigned int off = 1u + (unsigned int)(m >> 32);
      unsigned int jv = (iv + off) & 1023u;
      s_ij[k] = (iv << 16) | jv;
    }
    if (t == 0) s_p64 = NSTEPS;        // 6144 u32 consumed -> u64 idx 3072
  } else if (t == 0) {
    // exact sequential replay with rejections (P ~ 3e-6 per walk)
    int p = 0;
    for (int k = 0; k < NSTEPS; ++k) s_ij[k] = (u32at(p++) >> 22) << 16;
    for (int k = 0; k < NSTEPS; ++k) {
      unsigned long long m = (unsigned long long)u32at(p++) * 1023ull;
      unsigned int lo = (unsigned int)m;
      if (lo < 1023u) {
        while (lo < 4u) { m = (unsigned long long)u32at(p++) * 1023ull; lo = (unsigned int)m; }
      }
      unsigned int off = 1u + (unsigned int)(m >> 32);
      unsigned int iv = s_ij[k] >> 16;
      s_ij[k] = (iv << 16) | ((iv + off) & 1023u);
    }
    s_p64 = (p + 1) >> 1;
  }
  __syncthreads();

  // --- per-coord touch counts -> bases ---------------------------------
  for (int c = t; c < 1024; c += 256) s_cnt[c] = 0;
  __syncthreads();
  for (int k = t; k < NSTEPS; k += 256) {
    atomicAdd(&s_cnt[s_ij[k] >> 16], 1);
    atomicAdd(&s_cnt[s_ij[k] & 0xffffu], 1);
  }
  __syncthreads();
  if (t < 64) {
    int loc[16], tot = 0;
    #pragma unroll
    for (int q = 0; q < 16; ++q) { loc[q] = s_cnt[t * 16 + q]; tot += loc[q]; }
    int sc = tot;
    for (int off = 1; off < 64; off <<= 1) {
      int v = __shfl_up(sc, off);
      if (t >= off) sc += v;
    }
    int base = sc - tot;
    #pragma unroll
    for (int q = 0; q < 16; ++q) { s_base[t * 16 + q] = base; base += loc[q]; }
  }
  if (t == 0) s_base[1024] = 2 * NSTEPS;
  __syncthreads();

  // --- scatter (k,side) into buckets, sort, derive preds ----------------
  for (int c = t; c < 1024; c += 256) s_cnt[c] = 0;
  __syncthreads();
  for (int k = t; k < NSTEPS; k += 256) {
    unsigned int iv = s_ij[k] >> 16, jv = s_ij[k] & 0xffffu;
    int p1 = atomicAdd(&s_cnt[iv], 1);
    s_list[s_base[iv] + p1] = (unsigned short)(k << 1);
    int p2 = atomicAdd(&s_cnt[jv], 1);
    s_list[s_base[jv] + p2] = (unsigned short)((k << 1) | 1);
  }
  __syncthreads();
  for (int c = t; c < 1024; c += 256) {
    int b0 = s_base[c], b1 = s_base[c + 1];
    for (int a = b0 + 1; a < b1; ++a) {       // insertion sort (~6 elems)
      unsigned short v = s_list[a];
      int p = a;
      while (p > b0 && s_list[p - 1] > v) { s_list[p] = s_list[p - 1]; --p; }
      s_list[p] = v;
    }
    short prev = -1;
    for (int a = b0; a < b1; ++a) {
      int e = s_list[a]; int k = e >> 1;
      if (e & 1) s_predB[k] = prev; else s_predA[k] = prev;
      prev = (short)k;
    }
  }
  __syncthreads();

  // --- monotone relaxation to longest-path levels -----------------------
  for (int k = t; k < NSTEPS; k += 256) s_lev[k] = 1;
  __syncthreads();
  for (int it = 0; it < 300; ++it) {
    if (t == 0) s_changed = 0;
    __syncthreads();
    for (int k = t; k < NSTEPS; k += 256) {
      int la = s_predA[k] >= 0 ? (int)s_lev[s_predA[k]] : 0;
      int lb = s_predB[k] >= 0 ? (int)s_lev[s_predB[k]] : 0;
      int nl = 1 + (la > lb ? la : lb);
      if (nl > (int)s_lev[k]) {
        if (nl >= MAXLEV) { nl = MAXLEV - 1; diag[3] = 7.0e8f; }
        s_lev[k] = (unsigned short)nl; s_changed = 1;
      }
    }
    __syncthreads();
    int done = !s_changed;
    __syncthreads();
    if (done) break;
  }

  // --- histogram levels, padded bases (groups of 16) --------------------
  for (int L = t; L < MAXLEV; L += 256) s_lcnt[L] = 0;
  __syncthreads();
  for (int k = t; k < NSTEPS; k += 256) {
    atomicAdd(&s_lcnt[s_lev[k]], 1);
    atomicMax(&s_maxlev, (int)s_lev[k]);
  }
  __syncthreads();
  if (t == 0) {
    int run = 0;
    for (int L = 1; L <= s_maxlev; ++L) {
      s_lbase[L] = run;
      run += (s_lcnt[L] + 15) & ~15;
    }
    s_ns = run;
    hdr[w] = (run <= MAXS) ? run : MAXS;
    hdr[2 + w] = s_maxlev;
    if (run > MAXS) diag[3] = 6.0e8f;
  }
  __syncthreads();
  const int ns = (s_ns <= MAXS) ? s_ns : MAXS;
  // per-level GROUP bases (16 slots per group): glb[li] for li=0..nlev
  for (int L = 1 + t; L <= s_maxlev; L += 256) glbw[L - 1] = s_lbase[L] >> 4;
  if (t == 0) glbw[s_maxlev] = ns >> 4;

  uint4* ps = w ? ps1 : ps0;
  uint4 noop;
  noop.x = (1024u << 16) | 1024u;   // scratch coord (raw)
  noop.y = __float_as_uint(1.0f);
  noop.z = __float_as_uint(0.0f);
  noop.w = 0u;
  for (int s = t; s < ns; s += 256) ps[s] = noop;
  for (int L = t; L < MAXLEV; L += 256) s_lcnt[L] = 0;   // reuse as cursors
  __syncthreads();
  const int base64 = s_p64;
  for (int k = t; k < NSTEPS; k += 256) {
    int lv = s_lev[k];
    int pos = atomicAdd(&s_lcnt[lv], 1);
    int slot = s_lbase[lv] + pos;
    if (slot < MAXS) {
      unsigned long long v = raw[base64 + k];
      double d = (double)(v >> 11) * (1.0 / 9007199254740992.0);
      double ang = d * 6.283185307179586;
      uint4 ent;
      ent.x = s_ij[k];                 // raw coords; walk applies stride
      ent.y = __float_as_uint((float)cos(ang));
      ent.z = __float_as_uint((float)sin(ang));
      ent.w = 0u;
      ps[slot] = ent;
    }
  }
}

// ---------------- Kernel 2: level-parallel Kac walk (256 blocks x 4 cols) --
__device__ __forceinline__ void do_group(const uint4* __restrict__ SG, int g,
                                         float* __restrict__ L, int col, int slot) {
  uint4 e = SG[g * 16 + slot];
  const int i = (int)(e.x >> 16) * 5 + col, j = (int)(e.x & 0xffffu) * 5 + col;
  const float c = __uint_as_float(e.y), s = __uint_as_float(e.z);
  float xi = L[i], xj = L[j];
  L[i] = fmaf(c, xi, -s * xj);
  L[j] = fmaf(s, xi, c * xj);
}

__global__ __launch_bounds__(256) void walk_kernel(const uint4* __restrict__ ps0,
                                                   const uint4* __restrict__ ps1,
                                                   const int* __restrict__ hdr,
                                                   const int* __restrict__ glb0,
                                                   const int* __restrict__ glb1,
                                                   const float* __restrict__ W,
                                                   const float* __restrict__ vec,
                                                   unsigned short* __restrict__ Bh,
                                                   float* __restrict__ diag) {
  __shared__ float L[1025 * 5];      // 20.5 KB
  __shared__ uint4 SG[MAXS];         // 72 KB
  __shared__ int sGlb[MAXLEV + 1];   // 1 KB
  const int b = blockIdx.x;          // 0..255
  const int t = threadIdx.x;
  const int d0 = b * 4;
  const int wid = t >> 6, lane = t & 63;
  const int col = lane & 3, slot = lane >> 2;
  int ns0 = hdr[0]; if (ns0 > MAXS) ns0 = MAXS;
  int ns1 = hdr[1]; if (ns1 > MAXS) ns1 = MAXS;
  const int nlev0 = hdr[2], nlev1 = hdr[3];

  for (int idx = t; idx < 1025 * 4; idx += 256) {
    int c = idx >> 2, cc = idx & 3;
    L[c * 5 + cc] = (c == d0 + cc) ? 1.0f : 0.0f;
  }
  for (int s = t; s < ns0; s += 256) SG[s] = ps0[s];
  for (int li = t; li <= nlev0 && li <= MAXLEV; li += 256) sGlb[li] = glb0[li];
  __syncthreads();
  for (int li = 0; li < nlev0; ++li) {
    const int g1 = sGlb[li + 1];
    for (int g = sGlb[li] + wid; g < g1; g += 4) do_group(SG, g, L, col, slot);
    __syncthreads();
  }
  {  // Givens chains preserve unit norms
    bool bad = false;
    if (b == 0 && t < 4) {
      float ss = 0.0f;
      for (int c = 0; c < 1024; ++c) { float v = L[c * 5 + t]; ss += v * v; }
      bad = fabsf(ss - 1.0f) > 2.0e-3f;
    }
    unsigned long long bm = __ballot(bad);
    if (b == 0 && t == 0 && bm) diag[1] = 2.0e7f;
  }
  __syncthreads();
  for (int idx = t; idx < 1024 * 4; idx += 256) {
    int c = idx >> 2, cc = idx & 3;
    L[c * 5 + cc] *= vec[c];
  }
  for (int s = t; s < ns1; s += 256) SG[s] = ps1[s];
  __syncthreads();   // SG swap + vec-mul complete
  for (int li = t; li <= nlev1 && li <= MAXLEV; li += 256) sGlb[li] = glb1[li];
  __syncthreads();
  for (int li = 0; li < nlev1; ++li) {
    const int g1 = sGlb[li + 1];
    for (int g = sGlb[li] + wid; g < g1; g += 4) do_group(SG, g, L, col, slot);
    __syncthreads();
  }
  // B[e][d0+dl] = W[e][d0+dl] + M[e][d0+dl];  M[e][d0+dl] = L[e*5+dl]
  const int dl = t & 3;
  const int eb = t >> 2;
  for (int p = 0; p < 16; ++p) {
    int e = eb + p * 64;
    Bh[e * 1024 + d0 + dl] = f32_to_bf16(W[e * 1024 + d0 + dl] + L[e * 5 + dl]);
  }
}

// ---------------- Kernel 3: persistent GEMM (768 blocks x 2-3 tiles) -------
// r14-verified body: BK=64, f32-A via global_load_lds (pre-swizzled source,
// linear LDS dest), truncation-pack at frag read, LDS-bounce epilogue.
#if __has_builtin(__builtin_amdgcn_global_load_lds)
__device__ __forceinline__ void gload_lds16(const void* g, void* l) {
  __builtin_amdgcn_global_load_lds(
      (const __attribute__((address_space(1))) unsigned int*)g,
      (__attribute__((address_space(3))) unsigned int*)l, 16, 0, 0);
}
#define HAVE_GLDS 1
#else
#define HAVE_GLDS 0
#endif

__global__ __launch_bounds__(256) void gemm_kernel(const float* __restrict__ x,
                                                   const unsigned short* __restrict__ Bhg,
                                                   const float* __restrict__ bvec,
                                                   const float* __restrict__ diag,
                                                   float* __restrict__ out) {
#if HAVE_GLDS
  __shared__ char smem[49152];                 // A f32 32KB + B 16KB; Cst reuse
  char* Ash = smem;                            // [128 rows][16 chunks of 16B]
  char* Bsh = smem + 32768;                    // [128 rows][8 chunks of 16B]
  float* Cst = (float*)smem;                   // 64*132*4 = 33.8KB (reuse)
  const int t = threadIdx.x;
  const int l = t & 63, w = t >> 6;
  const int wr = w >> 1, wc = w & 1;
  const int lr = l & 15, lk = l >> 4;
  const int ldsu = w * 1024;                   // wave-uniform LDS base / round

  // staging geometry (per-lane constants, shared by all tiles)
  int arow[8], achb[8];
  #pragma unroll
  for (int p = 0; p < 8; ++p) {
    int idx = p * 256 + t;
    arow[p] = idx >> 4;
    achb[p] = ((idx & 15) ^ (arow[p] & 7)) << 4;   // pre-swizzled source byte
  }
  int brow[4], bchb[4];
  #pragma unroll
  for (int p = 0; p < 4; ++p) {
    int idx = p * 256 + t;
    brow[p] = idx >> 3;
    bchb[p] = ((idx & 7) ^ (brow[p] & 7)) << 4;
  }

  for (int tl = blockIdx.x; tl < 2048; tl += 768) {
    const int xcd = tl & 7;
    const int kk2 = tl >> 3;
    const int bm = xcd * 32 + (kk2 >> 3);      // 0..255 (stays on same XCD)
    const int bn = kk2 & 7;                    // 0..7
    const int m0 = bm * 128, n0 = bn * 128;

    f32x4 acc[4][4] = {};

    for (int kt = 0; kt < 16; ++kt) {
      #pragma unroll
      for (int p = 0; p < 8; ++p)
        gload_lds16((const char*)x + (size_t)(m0 + arow[p]) * 4096 + kt * 256 + achb[p],
                    Ash + p * 4096 + ldsu);
      #pragma unroll
      for (int p = 0; p < 4; ++p)
        gload_lds16((const char*)Bhg + (size_t)(n0 + brow[p]) * 2048 + kt * 128 + bchb[p],
                    Bsh + p * 4096 + ldsu);
      __syncthreads();   // vmcnt drained before barrier: LDS tiles complete

      #pragma unroll
      for (int kk = 0; kk < 64; kk += 32) {
        short8 af[4], bf[4];
        #pragma unroll
        for (int m4 = 0; m4 < 4; ++m4) {
          const int r = wr * 64 + m4 * 16 + lr;
          const int c0 = (kk >> 2) + lk * 2;       // even chunk
          const int c0s = c0 ^ (r & 7), c1s = (c0 + 1) ^ (r & 7);
          uint4 lo = *(const uint4*)(Ash + r * 256 + c0s * 16);
          uint4 hi = *(const uint4*)(Ash + r * 256 + c1s * 16);
          uint4 pk;
          pk.x = __byte_perm(lo.x, lo.y, 0x7632);  // truncation-pack f32->bf16
          pk.y = __byte_perm(lo.z, lo.w, 0x7632);
          pk.z = __byte_perm(hi.x, hi.y, 0x7632);
          pk.w = __byte_perm(hi.z, hi.w, 0x7632);
          af[m4] = __builtin_bit_cast(short8, pk);
        }
        #pragma unroll
        for (int n4 = 0; n4 < 4; ++n4) {
          const int r = wc * 64 + n4 * 16 + lr;
          const int cb = (kk * 2 + lk * 16) ^ ((r & 7) << 4);
          bf[n4] = *(const short8*)(Bsh + r * 128 + cb);
        }
        #pragma unroll
        for (int m4 = 0; m4 < 4; ++m4)
          #pragma unroll
          for (int n4 = 0; n4 < 4; ++n4)
            acc[m4][n4] = __builtin_amdgcn_mfma_f32_16x16x32_bf16(af[m4], bf[n4], acc[m4][n4], 0, 0, 0);
      }
      __syncthreads();
    }

    // epilogue: two 64-row halves staged through LDS, float4 row writes
    #pragma unroll
    for (int half = 0; half < 2; ++half) {
      if (wr == half) {
        #pragma unroll
        for (int n4 = 0; n4 < 4; ++n4) {
          const int col = wc * 64 + n4 * 16 + lr;
          const float bias = bvec[n0 + col];
          #pragma unroll
          for (int m4 = 0; m4 < 4; ++m4)
            #pragma unroll
            for (int q = 0; q < 4; ++q)
              Cst[(m4 * 16 + lk * 4 + q) * 132 + col] = acc[m4][n4][q] + bias;
        }
      }
      __syncthreads();
      {
        const int rg = t >> 5;
        const int c4 = (t & 31) * 4;
        #pragma unroll
        for (int rr = 0; rr < 8; ++rr) {
          int r = rg * 8 + rr;
          float4 v = *(const float4*)&Cst[r * 132 + c4];
          *(float4*)&out[(size_t)(m0 + half * 64 + r) * 1024 + (n0 + c4)] = v;
        }
      }
      __syncthreads();
    }
  }

  if (blockIdx.x == 0 && t == 0) {
    float dg = diag[0] + diag[1] + diag[3];
    if (dg != 0.0f) out[0] += dg;
  }
#else
  if (blockIdx.x == 0 && threadIdx.x == 0) out[0] = 8.0e8f;  // no-gload signal
#endif
}

__global__ void signal_kernel(float* out, float val) { out[0] = val; }

// ---------------------------------------------------------------------------
extern "C" void kernel_launch(void* const* d_in, const int* in_sizes, int n_in,
                              void* d_out, int out_size, void* d_ws, size_t ws_size,
                              hipStream_t stream) {
  const float* x    = (const float*)d_in[0];
  const float* W    = (const float*)d_in[1];
  const float* bvec = (const float*)d_in[2];
  const float* vec  = (const float*)d_in[3];
  float* out = (float*)d_out;

  const size_t MB = 1024 * 1024;
  // layout: diag @0 (64B), hdr @256 (32B), glb0 @1024 (1028B), glb1 @2560,
  //         ps0 @8192 (72KB), ps1 @98304 (72KB), Bh @1MB (2MB)
  const size_t need = 3 * MB;
  if (ws_size < need) {
    signal_kernel<<<1, 1, 0, stream>>>(out, 4.0e8f + (float)(ws_size >> 20) * 1000.0f);
    return;
  }
  float* diag = (float*)d_ws;
  int* hdr = (int*)((char*)d_ws + 256);
  int* glb0 = (int*)((char*)d_ws + 1024);
  int* glb1 = (int*)((char*)d_ws + 2560);
  uint4* ps0 = (uint4*)((char*)d_ws + 8192);
  uint4* ps1 = (uint4*)((char*)d_ws + 98304);
  unsigned short* Bh = (unsigned short*)((char*)d_ws + MB);

  hipMemsetAsync(diag, 0, 64, stream);
  gen_sched_kernel<<<2, 256, 0, stream>>>(ps0, ps1, hdr, glb0, glb1, diag);
  walk_kernel<<<256, 256, 0, stream>>>(ps0, ps1, hdr, glb0, glb1, W, vec, Bh, diag);
  gemm_kernel<<<768, 256, 0, stream>>>(x, Bh, bvec, diag, out);
}

// Round 19
// 269.870 us; speedup vs baseline: 1.3618x; 1.3618x over previous
//
#include <hip/hip_runtime.h>

// ---------------------------------------------------------------------------
// KacLayer: out = x @ (W^T + M) + b, where M = A2 diag(vec) A1 (Kac walks).
// numpy default_rng(4048)/default_rng(4049): PCG64 + SeedSequence (subtractive
// mix) + 32-bit buffered Lemire ints (low u32 half first) — verified r7.
// FINAL CONFIG (= r16, best measured 269us): level-parallel walk (256 blocks
// x 4 cols), r14-structure GEMM (BK=64 f32-A global_load_lds, pre-swizzled
// sources, truncation-pack frags, XCD-chunked mapping, LDS-bounce epilogue,
// 48KB LDS / 3 blocks/CU). r15 big-tile, r17 2-phase, r18 persistent-grid
// all regressed vs this (occupancy/VGPR effects dominate).
// ---------------------------------------------------------------------------

#define NSTEPS 3072
#define NCHUNK 26
#define NRAW (256 * NCHUNK)   // 6656 u64 (need 6144 + rejection slack)
#define MAXS 4608             // schedule slots per phase (3072 + pads)
#define MAXLEV 256

typedef __attribute__((ext_vector_type(8))) short short8;
typedef __attribute__((ext_vector_type(4))) float f32x4;

// ---------------- 128-bit PCG64 (numpy-exact) ------------------------------
struct U128 { unsigned long long lo, hi; };

__device__ __forceinline__ U128 mul128(U128 a, U128 b) {
  U128 r;
  r.lo = a.lo * b.lo;
  r.hi = __umul64hi(a.lo, b.lo) + a.lo * b.hi + a.hi * b.lo;
  return r;
}
__device__ __forceinline__ U128 add128(U128 a, U128 b) {
  U128 r; r.lo = a.lo + b.lo;
  r.hi = a.hi + b.hi + ((r.lo < a.lo) ? 1ull : 0ull);
  return r;
}
__device__ __forceinline__ U128 pcg_mult() {
  return U128{4865540595714422341ull, 2549297995355413924ull};
}
__device__ __forceinline__ U128 pcg_step(U128 st, U128 inc) {
  return add128(mul128(st, pcg_mult()), inc);
}
__device__ __forceinline__ unsigned long long pcg_out(U128 st) {
  unsigned long long x = st.hi ^ st.lo;
  unsigned int rot = (unsigned int)(st.hi >> 58);
  return (x >> rot) | (x << ((64u - rot) & 63u));
}

__device__ void pcg_seed(unsigned int seedval, U128* st, U128* inc) {
  unsigned int pool[4];
  unsigned int hc = 0x43b0d7e5u;                 // INIT_A
  auto hashmix = [&hc](unsigned int v) {
    v ^= hc; hc *= 0x931e8875u; v *= hc; v ^= v >> 16; return v;  // MULT_A
  };
  auto mixf = [](unsigned int x, unsigned int y) {
    unsigned int r = x * 0xca01f9ddu - y * 0x4973f715u;  // SUBTRACT (randutils)
    r ^= r >> 16; return r;
  };
  pool[0] = hashmix(seedval);
  pool[1] = hashmix(0u); pool[2] = hashmix(0u); pool[3] = hashmix(0u);
  for (int s = 0; s < 4; ++s)
    for (int d = 0; d < 4; ++d)
      if (s != d) pool[d] = mixf(pool[d], hashmix(pool[s]));
  unsigned int gc = 0x8b51f9ddu;                 // INIT_B
  unsigned int wv[8];
  for (int k = 0; k < 8; ++k) {
    unsigned int dv = pool[k & 3];
    dv ^= gc; gc *= 0x58f38dedu; dv *= gc; dv ^= dv >> 16;        // MULT_B
    wv[k] = dv;
  }
  unsigned long long o0 = (unsigned long long)wv[0] | ((unsigned long long)wv[1] << 32);
  unsigned long long o1 = (unsigned long long)wv[2] | ((unsigned long long)wv[3] << 32);
  unsigned long long o2 = (unsigned long long)wv[4] | ((unsigned long long)wv[5] << 32);
  unsigned long long o3 = (unsigned long long)wv[6] | ((unsigned long long)wv[7] << 32);
  U128 initstate = { o1, o0 };
  U128 initseq   = { o3, o2 };
  U128 icc; icc.lo = (initseq.lo << 1) | 1ull;
  icc.hi = (initseq.hi << 1) | (initseq.lo >> 63);
  *inc = icc;
  U128 s0 = {0ull, 0ull};
  s0 = pcg_step(s0, icc);
  s0 = add128(s0, initstate);
  s0 = pcg_step(s0, icc);
  *st = s0;
}

__device__ U128 pcg_advance(U128 st, U128 inc, unsigned long long delta) {
  U128 am = {1ull, 0ull}, ap = {0ull, 0ull};
  U128 cm = pcg_mult(), cp = inc;
  while (delta) {
    if (delta & 1ull) {
      am = mul128(am, cm);
      ap = add128(mul128(ap, cm), cp);
    }
    cp = mul128(add128(cm, U128{1ull, 0ull}), cp);
    cm = mul128(cm, cm);
    delta >>= 1;
  }
  return add128(mul128(st, am), ap);
}

__device__ __forceinline__ double first_draw(unsigned int seed) {
  U128 st, inc;
  pcg_seed(seed, &st, &inc);
  st = pcg_step(st, inc);
  return (double)(pcg_out(st) >> 11) * (1.0 / 9007199254740992.0);
}

__device__ __forceinline__ unsigned short f32_to_bf16(float f) {
  unsigned int u = __builtin_bit_cast(unsigned int, f);
  unsigned int r = u + 0x7fffu + ((u >> 16) & 1u);
  return (unsigned short)(r >> 16);
}

// ---------------- Kernel 1: schedule gen + level scheduling ----------------
__global__ __launch_bounds__(256) void gen_sched_kernel(uint4* __restrict__ ps0,
                                                        uint4* __restrict__ ps1,
                                                        int* __restrict__ hdr,
                                                        int* __restrict__ glb0,
                                                        int* __restrict__ glb1,
                                                        float* __restrict__ diag) {
  __shared__ unsigned long long raw[NRAW];          // 53 KB
  __shared__ unsigned int s_ij[NSTEPS];             // 12 KB
  __shared__ unsigned short s_list[2 * NSTEPS];     // 12 KB  (k<<1 | side)
  __shared__ short s_predA[NSTEPS];                 // 6 KB
  __shared__ short s_predB[NSTEPS];                 // 6 KB
  __shared__ unsigned short s_lev[NSTEPS];          // 6 KB
  __shared__ int s_cnt[1024];                       // 4 KB (also cursors)
  __shared__ int s_base[1025];                      // 4 KB
  __shared__ int s_lcnt[MAXLEV];                    // 1 KB (also cursors)
  __shared__ int s_lbase[MAXLEV];                   // 1 KB
  __shared__ int s_rej, s_p64, s_changed, s_maxlev, s_ns;
  const int w = blockIdx.x;     // walk: seed 4048 + w
  const int t = threadIdx.x;
  int* glbw = w ? glb1 : glb0;

  if (w == 0 && t == 0) {
    int m1 = first_draw(42u)    != 0.7739560485559633;
    int m2 = first_draw(0u)     != 0.6369616873214543;
    int m3 = first_draw(12345u) != 0.22733602246716966;
    if (m1 + m2 + m3 >= 2)
      diag[0] = 3.0e8f + (float)(m1 + 2 * m2 + 4 * m3) * 3.0e7f;
  }

  U128 st, inc;
  pcg_seed(4048u + (unsigned int)w, &st, &inc);
  U128 mine = pcg_advance(st, inc, (unsigned long long)t * NCHUNK);
  for (int q = 0; q < NCHUNK; ++q) {
    mine = pcg_step(mine, inc);
    raw[t * NCHUNK + q] = pcg_out(mine);
  }
  if (t == 0) { s_rej = 0; s_maxlev = 1; }
  __syncthreads();

  // u32 draw m: LOW half of u64 first, then HIGH (pcg64_next32 buffering)
  auto u32at = [&](int m) -> unsigned int {
    unsigned long long v = raw[m >> 1];
    return (m & 1) ? (unsigned int)(v >> 32) : (unsigned int)v;
  };

  for (int k = t; k < NSTEPS; k += 256) {
    unsigned long long m = (unsigned long long)u32at(NSTEPS + k) * 1023ull;
    if ((unsigned int)m < 4u) atomicAdd(&s_rej, 1);
  }
  __syncthreads();

  if (s_rej == 0) {
    for (int k = t; k < NSTEPS; k += 256) {
      unsigned int iv = u32at(k) >> 22;                 // (u32*1024)>>32
      unsigned long long m = (unsigned long long)u32at(NSTEPS + k) * 1023ull;
      unsigned int off = 1u + (unsigned int)(m >> 32);
      unsigned int jv = (iv + off) & 1023u;
      s_ij[k] = (iv << 16) | jv;
    }
    if (t == 0) s_p64 = NSTEPS;        // 6144 u32 consumed -> u64 idx 3072
  } else if (t == 0) {
    // exact sequential replay with rejections (P ~ 3e-6 per walk)
    int p = 0;
    for (int k = 0; k < NSTEPS; ++k) s_ij[k] = (u32at(p++) >> 22) << 16;
    for (int k = 0; k < NSTEPS; ++k) {
      unsigned long long m = (unsigned long long)u32at(p++) * 1023ull;
      unsigned int lo = (unsigned int)m;
      if (lo < 1023u) {
        while (lo < 4u) { m = (unsigned long long)u32at(p++) * 1023ull; lo = (unsigned int)m; }
      }
      unsigned int off = 1u + (unsigned int)(m >> 32);
      unsigned int iv = s_ij[k] >> 16;
      s_ij[k] = (iv << 16) | ((iv + off) & 1023u);
    }
    s_p64 = (p + 1) >> 1;
  }
  __syncthreads();

  // --- per-coord touch counts -> bases ---------------------------------
  for (int c = t; c < 1024; c += 256) s_cnt[c] = 0;
  __syncthreads();
  for (int k = t; k < NSTEPS; k += 256) {
    atomicAdd(&s_cnt[s_ij[k] >> 16], 1);
    atomicAdd(&s_cnt[s_ij[k] & 0xffffu], 1);
  }
  __syncthreads();
  if (t < 64) {
    int loc[16], tot = 0;
    #pragma unroll
    for (int q = 0; q < 16; ++q) { loc[q] = s_cnt[t * 16 + q]; tot += loc[q]; }
    int sc = tot;
    for (int off = 1; off < 64; off <<= 1) {
      int v = __shfl_up(sc, off);
      if (t >= off) sc += v;
    }
    int base = sc - tot;
    #pragma unroll
    for (int q = 0; q < 16; ++q) { s_base[t * 16 + q] = base; base += loc[q]; }
  }
  if (t == 0) s_base[1024] = 2 * NSTEPS;
  __syncthreads();

  // --- scatter (k,side) into buckets, sort, derive preds ----------------
  for (int c = t; c < 1024; c += 256) s_cnt[c] = 0;
  __syncthreads();
  for (int k = t; k < NSTEPS; k += 256) {
    unsigned int iv = s_ij[k] >> 16, jv = s_ij[k] & 0xffffu;
    int p1 = atomicAdd(&s_cnt[iv], 1);
    s_list[s_base[iv] + p1] = (unsigned short)(k << 1);
    int p2 = atomicAdd(&s_cnt[jv], 1);
    s_list[s_base[jv] + p2] = (unsigned short)((k << 1) | 1);
  }
  __syncthreads();
  for (int c = t; c < 1024; c += 256) {
    int b0 = s_base[c], b1 = s_base[c + 1];
    for (int a = b0 + 1; a < b1; ++a) {       // insertion sort (~6 elems)
      unsigned short v = s_list[a];
      int p = a;
      while (p > b0 && s_list[p - 1] > v) { s_list[p] = s_list[p - 1]; --p; }
      s_list[p] = v;
    }
    short prev = -1;
    for (int a = b0; a < b1; ++a) {
      int e = s_list[a]; int k = e >> 1;
      if (e & 1) s_predB[k] = prev; else s_predA[k] = prev;
      prev = (short)k;
    }
  }
  __syncthreads();

  // --- monotone relaxation to longest-path levels -----------------------
  for (int k = t; k < NSTEPS; k += 256) s_lev[k] = 1;
  __syncthreads();
  for (int it = 0; it < 300; ++it) {
    if (t == 0) s_changed = 0;
    __syncthreads();
    for (int k = t; k < NSTEPS; k += 256) {
      int la = s_predA[k] >= 0 ? (int)s_lev[s_predA[k]] : 0;
      int lb = s_predB[k] >= 0 ? (int)s_lev[s_predB[k]] : 0;
      int nl = 1 + (la > lb ? la : lb);
      if (nl > (int)s_lev[k]) {
        if (nl >= MAXLEV) { nl = MAXLEV - 1; diag[3] = 7.0e8f; }
        s_lev[k] = (unsigned short)nl; s_changed = 1;
      }
    }
    __syncthreads();
    int done = !s_changed;
    __syncthreads();
    if (done) break;
  }

  // --- histogram levels, padded bases (groups of 16) --------------------
  for (int L = t; L < MAXLEV; L += 256) s_lcnt[L] = 0;
  __syncthreads();
  for (int k = t; k < NSTEPS; k += 256) {
    atomicAdd(&s_lcnt[s_lev[k]], 1);
    atomicMax(&s_maxlev, (int)s_lev[k]);
  }
  __syncthreads();
  if (t == 0) {
    int run = 0;
    for (int L = 1; L <= s_maxlev; ++L) {
      s_lbase[L] = run;
      run += (s_lcnt[L] + 15) & ~15;
    }
    s_ns = run;
    hdr[w] = (run <= MAXS) ? run : MAXS;
    hdr[2 + w] = s_maxlev;
    if (run > MAXS) diag[3] = 6.0e8f;
  }
  __syncthreads();
  const int ns = (s_ns <= MAXS) ? s_ns : MAXS;
  // per-level GROUP bases (16 slots per group): glb[li] for li=0..nlev
  for (int L = 1 + t; L <= s_maxlev; L += 256) glbw[L - 1] = s_lbase[L] >> 4;
  if (t == 0) glbw[s_maxlev] = ns >> 4;

  uint4* ps = w ? ps1 : ps0;
  uint4 noop;
  noop.x = (1024u << 16) | 1024u;   // scratch coord (raw)
  noop.y = __float_as_uint(1.0f);
  noop.z = __float_as_uint(0.0f);
  noop.w = 0u;
  for (int s = t; s < ns; s += 256) ps[s] = noop;
  for (int L = t; L < MAXLEV; L += 256) s_lcnt[L] = 0;   // reuse as cursors
  __syncthreads();
  const int base64 = s_p64;
  for (int k = t; k < NSTEPS; k += 256) {
    int lv = s_lev[k];
    int pos = atomicAdd(&s_lcnt[lv], 1);
    int slot = s_lbase[lv] + pos;
    if (slot < MAXS) {
      unsigned long long v = raw[base64 + k];
      double d = (double)(v >> 11) * (1.0 / 9007199254740992.0);
      double ang = d * 6.283185307179586;
      uint4 ent;
      ent.x = s_ij[k];                 // raw coords; walk applies stride
      ent.y = __float_as_uint((float)cos(ang));
      ent.z = __float_as_uint((float)sin(ang));
      ent.w = 0u;
      ps[slot] = ent;
    }
  }
}

// ---------------- Kernel 2: level-parallel Kac walk (256 blocks x 4 cols) --
__device__ __forceinline__ void do_group(const uint4* __restrict__ SG, int g,
                                         float* __restrict__ L, int col, int slot) {
  uint4 e = SG[g * 16 + slot];
  const int i = (int)(e.x >> 16) * 5 + col, j = (int)(e.x & 0xffffu) * 5 + col;
  const float c = __uint_as_float(e.y), s = __uint_as_float(e.z);
  float xi = L[i], xj = L[j];
  L[i] = fmaf(c, xi, -s * xj);
  L[j] = fmaf(s, xi, c * xj);
}

__global__ __launch_bounds__(256) void walk_kernel(const uint4* __restrict__ ps0,
                                                   const uint4* __restrict__ ps1,
                                                   const int* __restrict__ hdr,
                                                   const int* __restrict__ glb0,
                                                   const int* __restrict__ glb1,
                                                   const float* __restrict__ W,
                                                   const float* __restrict__ vec,
                                                   unsigned short* __restrict__ Bh,
                                                   float* __restrict__ diag) {
  __shared__ float L[1025 * 5];      // 20.5 KB
  __shared__ uint4 SG[MAXS];         // 72 KB
  __shared__ int sGlb[MAXLEV + 1];   // 1 KB
  const int b = blockIdx.x;          // 0..255
  const int t = threadIdx.x;
  const int d0 = b * 4;
  const int wid = t >> 6, lane = t & 63;
  const int col = lane & 3, slot = lane >> 2;
  int ns0 = hdr[0]; if (ns0 > MAXS) ns0 = MAXS;
  int ns1 = hdr[1]; if (ns1 > MAXS) ns1 = MAXS;
  const int nlev0 = hdr[2], nlev1 = hdr[3];

  for (int idx = t; idx < 1025 * 4; idx += 256) {
    int c = idx >> 2, cc = idx & 3;
    L[c * 5 + cc] = (c == d0 + cc) ? 1.0f : 0.0f;
  }
  for (int s = t; s < ns0; s += 256) SG[s] = ps0[s];
  for (int li = t; li <= nlev0 && li <= MAXLEV; li += 256) sGlb[li] = glb0[li];
  __syncthreads();
  for (int li = 0; li < nlev0; ++li) {
    const int g1 = sGlb[li + 1];
    for (int g = sGlb[li] + wid; g < g1; g += 4) do_group(SG, g, L, col, slot);
    __syncthreads();
  }
  {  // Givens chains preserve unit norms
    bool bad = false;
    if (b == 0 && t < 4) {
      float ss = 0.0f;
      for (int c = 0; c < 1024; ++c) { float v = L[c * 5 + t]; ss += v * v; }
      bad = fabsf(ss - 1.0f) > 2.0e-3f;
    }
    unsigned long long bm = __ballot(bad);
    if (b == 0 && t == 0 && bm) diag[1] = 2.0e7f;
  }
  __syncthreads();
  for (int idx = t; idx < 1024 * 4; idx += 256) {
    int c = idx >> 2, cc = idx & 3;
    L[c * 5 + cc] *= vec[c];
  }
  for (int s = t; s < ns1; s += 256) SG[s] = ps1[s];
  __syncthreads();   // SG swap + vec-mul complete
  for (int li = t; li <= nlev1 && li <= MAXLEV; li += 256) sGlb[li] = glb1[li];
  __syncthreads();
  for (int li = 0; li < nlev1; ++li) {
    const int g1 = sGlb[li + 1];
    for (int g = sGlb[li] + wid; g < g1; g += 4) do_group(SG, g, L, col, slot);
    __syncthreads();
  }
  // B[e][d0+dl] = W[e][d0+dl] + M[e][d0+dl];  M[e][d0+dl] = L[e*5+dl]
  const int dl = t & 3;
  const int eb = t >> 2;
  for (int p = 0; p < 16; ++p) {
    int e = eb + p * 64;
    Bh[e * 1024 + d0 + dl] = f32_to_bf16(W[e * 1024 + d0 + dl] + L[e * 5 + dl]);
  }
}

// ---------------- Kernel 3: GEMM via global_load_lds (r14/r16, verified) ---
#if __has_builtin(__builtin_amdgcn_global_load_lds)
__device__ __forceinline__ void gload_lds16(const void* g, void* l) {
  __builtin_amdgcn_global_load_lds(
      (const __attribute__((address_space(1))) unsigned int*)g,
      (__attribute__((address_space(3))) unsigned int*)l, 16, 0, 0);
}
#define HAVE_GLDS 1
#else
#define HAVE_GLDS 0
#endif

__global__ __launch_bounds__(256) void gemm_kernel(const float* __restrict__ x,
                                                   const unsigned short* __restrict__ Bhg,
                                                   const float* __restrict__ bvec,
                                                   const float* __restrict__ diag,
                                                   float* __restrict__ out) {
#if HAVE_GLDS
  __shared__ char smem[49152];                 // A f32 32KB + B 16KB; Cst reuse
  char* Ash = smem;                            // [128 rows][16 chunks of 16B]
  char* Bsh = smem + 32768;                    // [128 rows][8 chunks of 16B]
  float* Cst = (float*)smem;                   // 64*132*4 = 33.8KB (reuse)
  const int t = threadIdx.x;
  const int bidx = blockIdx.x;
  const int xcd = bidx & 7;
  const int kk2 = bidx >> 3;
  const int bm = xcd * 32 + (kk2 >> 3);        // 0..255
  const int bn = kk2 & 7;                      // 0..7
  const int m0 = bm * 128, n0 = bn * 128;
  const int l = t & 63, w = t >> 6;
  const int wr = w >> 1, wc = w & 1;
  const int lr = l & 15, lk = l >> 4;
  const int ldsu = w * 1024;                   // wave-uniform LDS base per round

  // A: 8 rounds; idx=p*256+t: row=idx>>4, chunk=idx&15 (16B units, 64-f32 row)
  int arow[8], achb[8];
  #pragma unroll
  for (int p = 0; p < 8; ++p) {
    int idx = p * 256 + t;
    arow[p] = idx >> 4;
    achb[p] = ((idx & 15) ^ (arow[p] & 7)) << 4;   // pre-swizzled source byte
  }
  // B: 4 rounds; idx=p*256+t: row=idx>>3, chunk=idx&7 (16B units, 64-bf16 row)
  int brow[4], bchb[4];
  #pragma unroll
  for (int p = 0; p < 4; ++p) {
    int idx = p * 256 + t;
    brow[p] = idx >> 3;
    bchb[p] = ((idx & 7) ^ (brow[p] & 7)) << 4;
  }

  f32x4 acc[4][4] = {};

  for (int kt = 0; kt < 16; ++kt) {
    #pragma unroll
    for (int p = 0; p < 8; ++p)
      gload_lds16((const char*)x + (size_t)(m0 + arow[p]) * 4096 + kt * 256 + achb[p],
                  Ash + p * 4096 + ldsu);
    #pragma unroll
    for (int p = 0; p < 4; ++p)
      gload_lds16((const char*)Bhg + (size_t)(n0 + brow[p]) * 2048 + kt * 128 + bchb[p],
                  Bsh + p * 4096 + ldsu);
    __syncthreads();   // vmcnt drained before barrier: LDS tiles complete

    #pragma unroll
    for (int kk = 0; kk < 64; kk += 32) {
      short8 af[4], bf[4];
      #pragma unroll
      for (int m4 = 0; m4 < 4; ++m4) {
        const int r = wr * 64 + m4 * 16 + lr;
        const int c0 = (kk >> 2) + lk * 2;       // even chunk
        const int c0s = c0 ^ (r & 7), c1s = (c0 + 1) ^ (r & 7);
        uint4 lo = *(const uint4*)(Ash + r * 256 + c0s * 16);
        uint4 hi = *(const uint4*)(Ash + r * 256 + c1s * 16);
        uint4 pk;
        pk.x = __byte_perm(lo.x, lo.y, 0x7632);  // truncation-pack f32->bf16
        pk.y = __byte_perm(lo.z, lo.w, 0x7632);
        pk.z = __byte_perm(hi.x, hi.y, 0x7632);
        pk.w = __byte_perm(hi.z, hi.w, 0x7632);
        af[m4] = __builtin_bit_cast(short8, pk);
      }
      #pragma unroll
      for (int n4 = 0; n4 < 4; ++n4) {
        const int r = wc * 64 + n4 * 16 + lr;
        const int cb = (kk * 2 + lk * 16) ^ ((r & 7) << 4);
        bf[n4] = *(const short8*)(Bsh + r * 128 + cb);
      }
      #pragma unroll
      for (int m4 = 0; m4 < 4; ++m4)
        #pragma unroll
        for (int n4 = 0; n4 < 4; ++n4)
          acc[m4][n4] = __builtin_amdgcn_mfma_f32_16x16x32_bf16(af[m4], bf[n4], acc[m4][n4], 0, 0, 0);
    }
    __syncthreads();
  }

  // epilogue: two 64-row halves staged through LDS, float4 row writes
  #pragma unroll
  for (int half = 0; half < 2; ++half) {
    if (wr == half) {
      #pragma unroll
      for (int n4 = 0; n4 < 4; ++n4) {
        const int col = wc * 64 + n4 * 16 + lr;
        const float bias = bvec[n0 + col];
        #pragma unroll
        for (int m4 = 0; m4 < 4; ++m4)
          #pragma unroll
          for (int q = 0; q < 4; ++q)
            Cst[(m4 * 16 + lk * 4 + q) * 132 + col] = acc[m4][n4][q] + bias;
      }
    }
    __syncthreads();
    {
      const int rg = t >> 5;
      const int c4 = (t & 31) * 4;
      #pragma unroll
      for (int rr = 0; rr < 8; ++rr) {
        int r = rg * 8 + rr;
        float4 v = *(const float4*)&Cst[r * 132 + c4];
        *(float4*)&out[(size_t)(m0 + half * 64 + r) * 1024 + (n0 + c4)] = v;
      }
    }
    __syncthreads();
  }

  if (bidx == 0 && t == 0) {
    float dg = diag[0] + diag[1] + diag[3];
    if (dg != 0.0f) out[0] += dg;
  }
#else
  if (blockIdx.x == 0 && threadIdx.x == 0) out[0] = 8.0e8f;  // no-gload signal
#endif
}

__global__ void signal_kernel(float* out, float val) { out[0] = val; }

// ---------------------------------------------------------------------------
extern "C" void kernel_launch(void* const* d_in, const int* in_sizes, int n_in,
                              void* d_out, int out_size, void* d_ws, size_t ws_size,
                              hipStream_t stream) {
  const float* x    = (const float*)d_in[0];
  const float* W    = (const float*)d_in[1];
  const float* bvec = (const float*)d_in[2];
  const float* vec  = (const float*)d_in[3];
  float* out = (float*)d_out;

  const size_t MB = 1024 * 1024;
  // layout: diag @0 (64B), hdr @256 (32B), glb0 @1024 (1028B), glb1 @2560,
  //         ps0 @8192 (72KB), ps1 @98304 (72KB), Bh @1MB (2MB)
  const size_t need = 3 * MB;
  if (ws_size < need) {
    signal_kernel<<<1, 1, 0, stream>>>(out, 4.0e8f + (float)(ws_size >> 20) * 1000.0f);
    return;
  }
  float* diag = (float*)d_ws;
  int* hdr = (int*)((char*)d_ws + 256);
  int* glb0 = (int*)((char*)d_ws + 1024);
  int* glb1 = (int*)((char*)d_ws + 2560);
  uint4* ps0 = (uint4*)((char*)d_ws + 8192);
  uint4* ps1 = (uint4*)((char*)d_ws + 98304);
  unsigned short* Bh = (unsigned short*)((char*)d_ws + MB);

  hipMemsetAsync(diag, 0, 64, stream);
  gen_sched_kernel<<<2, 256, 0, stream>>>(ps0, ps1, hdr, glb0, glb1, diag);
  walk_kernel<<<256, 256, 0, stream>>>(ps0, ps1, hdr, glb0, glb1, W, vec, Bh, diag);
  gemm_kernel<<<2048, 256, 0, stream>>>(x, Bh, bvec, diag, out);
}

// Round 20
// 264.997 us; speedup vs baseline: 1.3868x; 1.0184x over previous
//
#include <hip/hip_runtime.h>

// ---------------------------------------------------------------------------
// KacLayer: out = x @ (W^T + M) + b, where M = A2 diag(vec) A1 (Kac walks).
// numpy default_rng(4048)/default_rng(4049): PCG64 + SeedSequence (subtractive
// mix) + 32-bit buffered Lemire ints (low u32 half first) — verified r7.
// r16 config + r20 GEMM repartition: SAME 128x128 BK=64 tile, SAME 48KB LDS,
// 512 threads / 8 waves (acc[2][4] per wave, 32 VGPR acc) -> target 24
// waves/CU (vs 12) for 2x latency hiding at identical memory behavior.
// ---------------------------------------------------------------------------

#define NSTEPS 3072
#define NCHUNK 26
#define NRAW (256 * NCHUNK)   // 6656 u64 (need 6144 + rejection slack)
#define MAXS 4608             // schedule slots per phase (3072 + pads)
#define MAXLEV 256

typedef __attribute__((ext_vector_type(8))) short short8;
typedef __attribute__((ext_vector_type(4))) float f32x4;

// ---------------- 128-bit PCG64 (numpy-exact) ------------------------------
struct U128 { unsigned long long lo, hi; };

__device__ __forceinline__ U128 mul128(U128 a, U128 b) {
  U128 r;
  r.lo = a.lo * b.lo;
  r.hi = __umul64hi(a.lo, b.lo) + a.lo * b.hi + a.hi * b.lo;
  return r;
}
__device__ __forceinline__ U128 add128(U128 a, U128 b) {
  U128 r; r.lo = a.lo + b.lo;
  r.hi = a.hi + b.hi + ((r.lo < a.lo) ? 1ull : 0ull);
  return r;
}
__device__ __forceinline__ U128 pcg_mult() {
  return U128{4865540595714422341ull, 2549297995355413924ull};
}
__device__ __forceinline__ U128 pcg_step(U128 st, U128 inc) {
  return add128(mul128(st, pcg_mult()), inc);
}
__device__ __forceinline__ unsigned long long pcg_out(U128 st) {
  unsigned long long x = st.hi ^ st.lo;
  unsigned int rot = (unsigned int)(st.hi >> 58);
  return (x >> rot) | (x << ((64u - rot) & 63u));
}

__device__ void pcg_seed(unsigned int seedval, U128* st, U128* inc) {
  unsigned int pool[4];
  unsigned int hc = 0x43b0d7e5u;                 // INIT_A
  auto hashmix = [&hc](unsigned int v) {
    v ^= hc; hc *= 0x931e8875u; v *= hc; v ^= v >> 16; return v;  // MULT_A
  };
  auto mixf = [](unsigned int x, unsigned int y) {
    unsigned int r = x * 0xca01f9ddu - y * 0x4973f715u;  // SUBTRACT (randutils)
    r ^= r >> 16; return r;
  };
  pool[0] = hashmix(seedval);
  pool[1] = hashmix(0u); pool[2] = hashmix(0u); pool[3] = hashmix(0u);
  for (int s = 0; s < 4; ++s)
    for (int d = 0; d < 4; ++d)
      if (s != d) pool[d] = mixf(pool[d], hashmix(pool[s]));
  unsigned int gc = 0x8b51f9ddu;                 // INIT_B
  unsigned int wv[8];
  for (int k = 0; k < 8; ++k) {
    unsigned int dv = pool[k & 3];
    dv ^= gc; gc *= 0x58f38dedu; dv *= gc; dv ^= dv >> 16;        // MULT_B
    wv[k] = dv;
  }
  unsigned long long o0 = (unsigned long long)wv[0] | ((unsigned long long)wv[1] << 32);
  unsigned long long o1 = (unsigned long long)wv[2] | ((unsigned long long)wv[3] << 32);
  unsigned long long o2 = (unsigned long long)wv[4] | ((unsigned long long)wv[5] << 32);
  unsigned long long o3 = (unsigned long long)wv[6] | ((unsigned long long)wv[7] << 32);
  U128 initstate = { o1, o0 };
  U128 initseq   = { o3, o2 };
  U128 icc; icc.lo = (initseq.lo << 1) | 1ull;
  icc.hi = (initseq.hi << 1) | (initseq.lo >> 63);
  *inc = icc;
  U128 s0 = {0ull, 0ull};
  s0 = pcg_step(s0, icc);
  s0 = add128(s0, initstate);
  s0 = pcg_step(s0, icc);
  *st = s0;
}

__device__ U128 pcg_advance(U128 st, U128 inc, unsigned long long delta) {
  U128 am = {1ull, 0ull}, ap = {0ull, 0ull};
  U128 cm = pcg_mult(), cp = inc;
  while (delta) {
    if (delta & 1ull) {
      am = mul128(am, cm);
      ap = add128(mul128(ap, cm), cp);
    }
    cp = mul128(add128(cm, U128{1ull, 0ull}), cp);
    cm = mul128(cm, cm);
    delta >>= 1;
  }
  return add128(mul128(st, am), ap);
}

__device__ __forceinline__ double first_draw(unsigned int seed) {
  U128 st, inc;
  pcg_seed(seed, &st, &inc);
  st = pcg_step(st, inc);
  return (double)(pcg_out(st) >> 11) * (1.0 / 9007199254740992.0);
}

__device__ __forceinline__ unsigned short f32_to_bf16(float f) {
  unsigned int u = __builtin_bit_cast(unsigned int, f);
  unsigned int r = u + 0x7fffu + ((u >> 16) & 1u);
  return (unsigned short)(r >> 16);
}

// ---------------- Kernel 1: schedule gen + level scheduling ----------------
__global__ __launch_bounds__(256) void gen_sched_kernel(uint4* __restrict__ ps0,
                                                        uint4* __restrict__ ps1,
                                                        int* __restrict__ hdr,
                                                        int* __restrict__ glb0,
                                                        int* __restrict__ glb1,
                                                        float* __restrict__ diag) {
  __shared__ unsigned long long raw[NRAW];          // 53 KB
  __shared__ unsigned int s_ij[NSTEPS];             // 12 KB
  __shared__ unsigned short s_list[2 * NSTEPS];     // 12 KB  (k<<1 | side)
  __shared__ short s_predA[NSTEPS];                 // 6 KB
  __shared__ short s_predB[NSTEPS];                 // 6 KB
  __shared__ unsigned short s_lev[NSTEPS];          // 6 KB
  __shared__ int s_cnt[1024];                       // 4 KB (also cursors)
  __shared__ int s_base[1025];                      // 4 KB
  __shared__ int s_lcnt[MAXLEV];                    // 1 KB (also cursors)
  __shared__ int s_lbase[MAXLEV];                   // 1 KB
  __shared__ int s_rej, s_p64, s_changed, s_maxlev, s_ns;
  const int w = blockIdx.x;     // walk: seed 4048 + w
  const int t = threadIdx.x;
  int* glbw = w ? glb1 : glb0;

  if (w == 0 && t == 0) {
    int m1 = first_draw(42u)    != 0.7739560485559633;
    int m2 = first_draw(0u)     != 0.6369616873214543;
    int m3 = first_draw(12345u) != 0.22733602246716966;
    if (m1 + m2 + m3 >= 2)
      diag[0] = 3.0e8f + (float)(m1 + 2 * m2 + 4 * m3) * 3.0e7f;
  }

  U128 st, inc;
  pcg_seed(4048u + (unsigned int)w, &st, &inc);
  U128 mine = pcg_advance(st, inc, (unsigned long long)t * NCHUNK);
  for (int q = 0; q < NCHUNK; ++q) {
    mine = pcg_step(mine, inc);
    raw[t * NCHUNK + q] = pcg_out(mine);
  }
  if (t == 0) { s_rej = 0; s_maxlev = 1; }
  __syncthreads();

  // u32 draw m: LOW half of u64 first, then HIGH (pcg64_next32 buffering)
  auto u32at = [&](int m) -> unsigned int {
    unsigned long long v = raw[m >> 1];
    return (m & 1) ? (unsigned int)(v >> 32) : (unsigned int)v;
  };

  for (int k = t; k < NSTEPS; k += 256) {
    unsigned long long m = (unsigned long long)u32at(NSTEPS + k) * 1023ull;
    if ((unsigned int)m < 4u) atomicAdd(&s_rej, 1);
  }
  __syncthreads();

  if (s_rej == 0) {
    for (int k = t; k < NSTEPS; k += 256) {
      unsigned int iv = u32at(k) >> 22;                 // (u32*1024)>>32
      unsigned long long m = (unsigned long long)u32at(NSTEPS + k) * 1023ull;
      unsigned int off = 1u + (unsigned int)(m >> 32);
      unsigned int jv = (iv + off) & 1023u;
      s_ij[k] = (iv << 16) | jv;
    }
    if (t == 0) s_p64 = NSTEPS;        // 6144 u32 consumed -> u64 idx 3072
  } else if (t == 0) {
    // exact sequential replay with rejections (P ~ 3e-6 per walk)
    int p = 0;
    for (int k = 0; k < NSTEPS; ++k) s_ij[k] = (u32at(p++) >> 22) << 16;
    for (int k = 0; k < NSTEPS; ++k) {
      unsigned long long m = (unsigned long long)u32at(p++) * 1023ull;
      unsigned int lo = (unsigned int)m;
      if (lo < 1023u) {
        while (lo < 4u) { m = (unsigned long long)u32at(p++) * 1023ull; lo = (unsigned int)m; }
      }
      unsigned int off = 1u + (unsigned int)(m >> 32);
      unsigned int iv = s_ij[k] >> 16;
      s_ij[k] = (iv << 16) | ((iv + off) & 1023u);
    }
    s_p64 = (p + 1) >> 1;
  }
  __syncthreads();

  // --- per-coord touch counts -> bases ---------------------------------
  for (int c = t; c < 1024; c += 256) s_cnt[c] = 0;
  __syncthreads();
  for (int k = t; k < NSTEPS; k += 256) {
    atomicAdd(&s_cnt[s_ij[k] >> 16], 1);
    atomicAdd(&s_cnt[s_ij[k] & 0xffffu], 1);
  }
  __syncthreads();
  if (t < 64) {
    int loc[16], tot = 0;
    #pragma unroll
    for (int q = 0; q < 16; ++q) { loc[q] = s_cnt[t * 16 + q]; tot += loc[q]; }
    int sc = tot;
    for (int off = 1; off < 64; off <<= 1) {
      int v = __shfl_up(sc, off);
      if (t >= off) sc += v;
    }
    int base = sc - tot;
    #pragma unroll
    for (int q = 0; q < 16; ++q) { s_base[t * 16 + q] = base; base += loc[q]; }
  }
  if (t == 0) s_base[1024] = 2 * NSTEPS;
  __syncthreads();

  // --- scatter (k,side) into buckets, sort, derive preds ----------------
  for (int c = t; c < 1024; c += 256) s_cnt[c] = 0;
  __syncthreads();
  for (int k = t; k < NSTEPS; k += 256) {
    unsigned int iv = s_ij[k] >> 16, jv = s_ij[k] & 0xffffu;
    int p1 = atomicAdd(&s_cnt[iv], 1);
    s_list[s_base[iv] + p1] = (unsigned short)(k << 1);
    int p2 = atomicAdd(&s_cnt[jv], 1);
    s_list[s_base[jv] + p2] = (unsigned short)((k << 1) | 1);
  }
  __syncthreads();
  for (int c = t; c < 1024; c += 256) {
    int b0 = s_base[c], b1 = s_base[c + 1];
    for (int a = b0 + 1; a < b1; ++a) {       // insertion sort (~6 elems)
      unsigned short v = s_list[a];
      int p = a;
      while (p > b0 && s_list[p - 1] > v) { s_list[p] = s_list[p - 1]; --p; }
      s_list[p] = v;
    }
    short prev = -1;
    for (int a = b0; a < b1; ++a) {
      int e = s_list[a]; int k = e >> 1;
      if (e & 1) s_predB[k] = prev; else s_predA[k] = prev;
      prev = (short)k;
    }
  }
  __syncthreads();

  // --- monotone relaxation to longest-path levels -----------------------
  for (int k = t; k < NSTEPS; k += 256) s_lev[k] = 1;
  __syncthreads();
  for (int it = 0; it < 300; ++it) {
    if (t == 0) s_changed = 0;
    __syncthreads();
    for (int k = t; k < NSTEPS; k += 256) {
      int la = s_predA[k] >= 0 ? (int)s_lev[s_predA[k]] : 0;
      int lb = s_predB[k] >= 0 ? (int)s_lev[s_predB[k]] : 0;
      int nl = 1 + (la > lb ? la : lb);
      if (nl > (int)s_lev[k]) {
        if (nl >= MAXLEV) { nl = MAXLEV - 1; diag[3] = 7.0e8f; }
        s_lev[k] = (unsigned short)nl; s_changed = 1;
      }
    }
    __syncthreads();
    int done = !s_changed;
    __syncthreads();
    if (done) break;
  }

  // --- histogram levels, padded bases (groups of 16) --------------------
  for (int L = t; L < MAXLEV; L += 256) s_lcnt[L] = 0;
  __syncthreads();
  for (int k = t; k < NSTEPS; k += 256) {
    atomicAdd(&s_lcnt[s_lev[k]], 1);
    atomicMax(&s_maxlev, (int)s_lev[k]);
  }
  __syncthreads();
  if (t == 0) {
    int run = 0;
    for (int L = 1; L <= s_maxlev; ++L) {
      s_lbase[L] = run;
      run += (s_lcnt[L] + 15) & ~15;
    }
    s_ns = run;
    hdr[w] = (run <= MAXS) ? run : MAXS;
    hdr[2 + w] = s_maxlev;
    if (run > MAXS) diag[3] = 6.0e8f;
  }
  __syncthreads();
  const int ns = (s_ns <= MAXS) ? s_ns : MAXS;
  // per-level GROUP bases (16 slots per group): glb[li] for li=0..nlev
  for (int L = 1 + t; L <= s_maxlev; L += 256) glbw[L - 1] = s_lbase[L] >> 4;
  if (t == 0) glbw[s_maxlev] = ns >> 4;

  uint4* ps = w ? ps1 : ps0;
  uint4 noop;
  noop.x = (1024u << 16) | 1024u;   // scratch coord (raw)
  noop.y = __float_as_uint(1.0f);
  noop.z = __float_as_uint(0.0f);
  noop.w = 0u;
  for (int s = t; s < ns; s += 256) ps[s] = noop;
  for (int L = t; L < MAXLEV; L += 256) s_lcnt[L] = 0;   // reuse as cursors
  __syncthreads();
  const int base64 = s_p64;
  for (int k = t; k < NSTEPS; k += 256) {
    int lv = s_lev[k];
    int pos = atomicAdd(&s_lcnt[lv], 1);
    int slot = s_lbase[lv] + pos;
    if (slot < MAXS) {
      unsigned long long v = raw[base64 + k];
      double d = (double)(v >> 11) * (1.0 / 9007199254740992.0);
      double ang = d * 6.283185307179586;
      uint4 ent;
      ent.x = s_ij[k];                 // raw coords; walk applies stride
      ent.y = __float_as_uint((float)cos(ang));
      ent.z = __float_as_uint((float)sin(ang));
      ent.w = 0u;
      ps[slot] = ent;
    }
  }
}

// ---------------- Kernel 2: level-parallel Kac walk (256 blocks x 4 cols) --
__device__ __forceinline__ void do_group(const uint4* __restrict__ SG, int g,
                                         float* __restrict__ L, int col, int slot) {
  uint4 e = SG[g * 16 + slot];
  const int i = (int)(e.x >> 16) * 5 + col, j = (int)(e.x & 0xffffu) * 5 + col;
  const float c = __uint_as_float(e.y), s = __uint_as_float(e.z);
  float xi = L[i], xj = L[j];
  L[i] = fmaf(c, xi, -s * xj);
  L[j] = fmaf(s, xi, c * xj);
}

__global__ __launch_bounds__(256) void walk_kernel(const uint4* __restrict__ ps0,
                                                   const uint4* __restrict__ ps1,
                                                   const int* __restrict__ hdr,
                                                   const int* __restrict__ glb0,
                                                   const int* __restrict__ glb1,
                                                   const float* __restrict__ W,
                                                   const float* __restrict__ vec,
                                                   unsigned short* __restrict__ Bh,
                                                   float* __restrict__ diag) {
  __shared__ float L[1025 * 5];      // 20.5 KB
  __shared__ uint4 SG[MAXS];         // 72 KB
  __shared__ int sGlb[MAXLEV + 1];   // 1 KB
  const int b = blockIdx.x;          // 0..255
  const int t = threadIdx.x;
  const int d0 = b * 4;
  const int wid = t >> 6, lane = t & 63;
  const int col = lane & 3, slot = lane >> 2;
  int ns0 = hdr[0]; if (ns0 > MAXS) ns0 = MAXS;
  int ns1 = hdr[1]; if (ns1 > MAXS) ns1 = MAXS;
  const int nlev0 = hdr[2], nlev1 = hdr[3];

  for (int idx = t; idx < 1025 * 4; idx += 256) {
    int c = idx >> 2, cc = idx & 3;
    L[c * 5 + cc] = (c == d0 + cc) ? 1.0f : 0.0f;
  }
  for (int s = t; s < ns0; s += 256) SG[s] = ps0[s];
  for (int li = t; li <= nlev0 && li <= MAXLEV; li += 256) sGlb[li] = glb0[li];
  __syncthreads();
  for (int li = 0; li < nlev0; ++li) {
    const int g1 = sGlb[li + 1];
    for (int g = sGlb[li] + wid; g < g1; g += 4) do_group(SG, g, L, col, slot);
    __syncthreads();
  }
  {  // Givens chains preserve unit norms
    bool bad = false;
    if (b == 0 && t < 4) {
      float ss = 0.0f;
      for (int c = 0; c < 1024; ++c) { float v = L[c * 5 + t]; ss += v * v; }
      bad = fabsf(ss - 1.0f) > 2.0e-3f;
    }
    unsigned long long bm = __ballot(bad);
    if (b == 0 && t == 0 && bm) diag[1] = 2.0e7f;
  }
  __syncthreads();
  for (int idx = t; idx < 1024 * 4; idx += 256) {
    int c = idx >> 2, cc = idx & 3;
    L[c * 5 + cc] *= vec[c];
  }
  for (int s = t; s < ns1; s += 256) SG[s] = ps1[s];
  __syncthreads();   // SG swap + vec-mul complete
  for (int li = t; li <= nlev1 && li <= MAXLEV; li += 256) sGlb[li] = glb1[li];
  __syncthreads();
  for (int li = 0; li < nlev1; ++li) {
    const int g1 = sGlb[li + 1];
    for (int g = sGlb[li] + wid; g < g1; g += 4) do_group(SG, g, L, col, slot);
    __syncthreads();
  }
  // B[e][d0+dl] = W[e][d0+dl] + M[e][d0+dl];  M[e][d0+dl] = L[e*5+dl]
  const int dl = t & 3;
  const int eb = t >> 2;
  for (int p = 0; p < 16; ++p) {
    int e = eb + p * 64;
    Bh[e * 1024 + d0 + dl] = f32_to_bf16(W[e * 1024 + d0 + dl] + L[e * 5 + dl]);
  }
}

// ---------------- Kernel 3: GEMM 128x128 BK=64, 512 threads / 8 waves ------
// Same tile, LDS (48KB) and memory behavior as r16; wave grid 4x2, per-wave
// acc[2][4] (32 VGPR) -> target 24 waves/CU for 2x latency hiding.
#if __has_builtin(__builtin_amdgcn_global_load_lds)
__device__ __forceinline__ void gload_lds16(const void* g, void* l) {
  __builtin_amdgcn_global_load_lds(
      (const __attribute__((address_space(1))) unsigned int*)g,
      (__attribute__((address_space(3))) unsigned int*)l, 16, 0, 0);
}
#define HAVE_GLDS 1
#else
#define HAVE_GLDS 0
#endif

__global__ __launch_bounds__(512) void gemm_kernel(const float* __restrict__ x,
                                                   const unsigned short* __restrict__ Bhg,
                                                   const float* __restrict__ bvec,
                                                   const float* __restrict__ diag,
                                                   float* __restrict__ out) {
#if HAVE_GLDS
  __shared__ char smem[49152];                 // A f32 32KB + B 16KB; Cst reuse
  char* Ash = smem;                            // [128 rows][16 chunks of 16B]
  char* Bsh = smem + 32768;                    // [128 rows][8 chunks of 16B]
  float* Cst = (float*)smem;                   // 64*132*4 = 33.8KB (reuse)
  const int t = threadIdx.x;
  const int bidx = blockIdx.x;
  const int xcd = bidx & 7;
  const int kk2 = bidx >> 3;
  const int bm = xcd * 32 + (kk2 >> 3);        // 0..255
  const int bn = kk2 & 7;                      // 0..7
  const int m0 = bm * 128, n0 = bn * 128;
  const int l = t & 63, w = t >> 6;            // 8 waves
  const int wr = w >> 1, wc = w & 1;           // 4x2 wave grid: 32 rows x 64 cols
  const int lr = l & 15, lk = l >> 4;
  const int ldsu = w * 1024;                   // wave-uniform LDS base per round

  // A: 4 rounds; idx=p*512+t: row=idx>>4 (0..127), chunk=idx&15 (16B units)
  int arow[4], achb[4];
  #pragma unroll
  for (int p = 0; p < 4; ++p) {
    int idx = p * 512 + t;
    arow[p] = idx >> 4;
    achb[p] = ((idx & 15) ^ (arow[p] & 7)) << 4;   // pre-swizzled source byte
  }
  // B: 2 rounds; idx=p*512+t: row=idx>>3 (0..127), chunk=idx&7
  int brow[2], bchb[2];
  #pragma unroll
  for (int p = 0; p < 2; ++p) {
    int idx = p * 512 + t;
    brow[p] = idx >> 3;
    bchb[p] = ((idx & 7) ^ (brow[p] & 7)) << 4;
  }

  f32x4 acc[2][4] = {};

  for (int kt = 0; kt < 16; ++kt) {
    #pragma unroll
    for (int p = 0; p < 4; ++p)
      gload_lds16((const char*)x + (size_t)(m0 + arow[p]) * 4096 + kt * 256 + achb[p],
                  Ash + p * 8192 + ldsu);
    #pragma unroll
    for (int p = 0; p < 2; ++p)
      gload_lds16((const char*)Bhg + (size_t)(n0 + brow[p]) * 2048 + kt * 128 + bchb[p],
                  Bsh + p * 8192 + ldsu);
    __syncthreads();   // vmcnt drained before barrier: LDS tiles complete

    #pragma unroll
    for (int kk = 0; kk < 64; kk += 32) {
      short8 af[2], bf[4];
      #pragma unroll
      for (int m4 = 0; m4 < 2; ++m4) {
        const int r = wr * 32 + m4 * 16 + lr;
        const int c0 = (kk >> 2) + lk * 2;       // even chunk
        const int c0s = c0 ^ (r & 7), c1s = (c0 + 1) ^ (r & 7);
        uint4 lo = *(const uint4*)(Ash + r * 256 + c0s * 16);
        uint4 hi = *(const uint4*)(Ash + r * 256 + c1s * 16);
        uint4 pk;
        pk.x = __byte_perm(lo.x, lo.y, 0x7632);  // truncation-pack f32->bf16
        pk.y = __byte_perm(lo.z, lo.w, 0x7632);
        pk.z = __byte_perm(hi.x, hi.y, 0x7632);
        pk.w = __byte_perm(hi.z, hi.w, 0x7632);
        af[m4] = __builtin_bit_cast(short8, pk);
      }
      #pragma unroll
      for (int n4 = 0; n4 < 4; ++n4) {
        const int r = wc * 64 + n4 * 16 + lr;
        const int cb = (kk * 2 + lk * 16) ^ ((r & 7) << 4);
        bf[n4] = *(const short8*)(Bsh + r * 128 + cb);
      }
      #pragma unroll
      for (int m4 = 0; m4 < 2; ++m4)
        #pragma unroll
        for (int n4 = 0; n4 < 4; ++n4)
          acc[m4][n4] = __builtin_amdgcn_mfma_f32_16x16x32_bf16(af[m4], bf[n4], acc[m4][n4], 0, 0, 0);
    }
    __syncthreads();
  }

  // epilogue: two 64-row halves staged through LDS, float4 row writes
  #pragma unroll
  for (int half = 0; half < 2; ++half) {
    if ((wr >> 1) == half) {                   // waves wr in {2h, 2h+1}
      #pragma unroll
      for (int n4 = 0; n4 < 4; ++n4) {
        const int col = wc * 64 + n4 * 16 + lr;
        const float bias = bvec[n0 + col];
        #pragma unroll
        for (int m4 = 0; m4 < 2; ++m4)
          #pragma unroll
          for (int q = 0; q < 4; ++q)
            Cst[((wr & 1) * 32 + m4 * 16 + lk * 4 + q) * 132 + col] = acc[m4][n4][q] + bias;
      }
    }
    __syncthreads();
    {
      const int rg = t >> 5;                   // 0..15
      const int c4 = (t & 31) * 4;
      #pragma unroll
      for (int rr = 0; rr < 4; ++rr) {
        int r = rg + rr * 16;
        float4 v = *(const float4*)&Cst[r * 132 + c4];
        *(float4*)&out[(size_t)(m0 + half * 64 + r) * 1024 + (n0 + c4)] = v;
      }
    }
    __syncthreads();
  }

  if (bidx == 0 && t == 0) {
    float dg = diag[0] + diag[1] + diag[3];
    if (dg != 0.0f) out[0] += dg;
  }
#else
  if (blockIdx.x == 0 && threadIdx.x == 0) out[0] = 8.0e8f;  // no-gload signal
#endif
}

__global__ void signal_kernel(float* out, float val) { out[0] = val; }

// ---------------------------------------------------------------------------
extern "C" void kernel_launch(void* const* d_in, const int* in_sizes, int n_in,
                              void* d_out, int out_size, void* d_ws, size_t ws_size,
                              hipStream_t stream) {
  const float* x    = (const float*)d_in[0];
  const float* W    = (const float*)d_in[1];
  const float* bvec = (const float*)d_in[2];
  const float* vec  = (const float*)d_in[3];
  float* out = (float*)d_out;

  const size_t MB = 1024 * 1024;
  // layout: diag @0 (64B), hdr @256 (32B), glb0 @1024 (1028B), glb1 @2560,
  //         ps0 @8192 (72KB), ps1 @98304 (72KB), Bh @1MB (2MB)
  const size_t need = 3 * MB;
  if (ws_size < need) {
    signal_kernel<<<1, 1, 0, stream>>>(out, 4.0e8f + (float)(ws_size >> 20) * 1000.0f);
    return;
  }
  float* diag = (float*)d_ws;
  int* hdr = (int*)((char*)d_ws + 256);
  int* glb0 = (int*)((char*)d_ws + 1024);
  int* glb1 = (int*)((char*)d_ws + 2560);
  uint4* ps0 = (uint4*)((char*)d_ws + 8192);
  uint4* ps1 = (uint4*)((char*)d_ws + 98304);
  unsigned short* Bh = (unsigned short*)((char*)d_ws + MB);

  hipMemsetAsync(diag, 0, 64, stream);
  gen_sched_kernel<<<2, 256, 0, stream>>>(ps0, ps1, hdr, glb0, glb1, diag);
  walk_kernel<<<256, 256, 0, stream>>>(ps0, ps1, hdr, glb0, glb1, W, vec, Bh, diag);
  gemm_kernel<<<2048, 512, 0, stream>>>(x, Bh, bvec, diag, out);
}